// Round 19
// baseline (173.701 us; speedup 1.0000x reference)
//
#include <hip/hip_runtime.h>
#include <hip/hip_bf16.h>

// spatial_attention: out = weights @ P1 + P2 ; P1 = H W1^T ; P2 = H W2^T + bias
//   Domain uniform (runtime-verified) -> weights fast path: w = relu(dval - dist).
//   R18 lesson: every __syncthreads drains vmcnt(0) -> per-chunk dbuf never overlaps.
//   Fix: B fits entirely in LDS (128KB) -> stage ONCE, K-loop has ZERO barriers.
//   Blocks: grid 256 (block = batch b), 1024 thr = 16 waves (wr 8 x 32 rows, wc 2 x 128 d),
//   LDS = 4 regions x [256 rows][128B] (R18-verified XOR-swizzle layout, 0 conflicts).
//   K0  : Wbf = bf16(W); k0_check -> {dval, uniform}
//   k2a : weights -> weBuf (pre-scaled bf16), wave-per-row
//   kP  : stage W1 -> P1T[b] ; restage W2 -> P2[b] (+bias). 3 barriers total.
//   kOut: stage P1T[b] -> out = weBuf @ P1T + P2. 1 barrier.
// Workspace: Wbf 512KB @0 ; flag @512KB ; P1T 32MB @1MB ; P2 32MB @33MB ; weBuf 32MB @65MB

typedef __attribute__((ext_vector_type(4))) float  f32x4;
typedef __attribute__((ext_vector_type(8))) short  bf16x8;
typedef __attribute__((ext_vector_type(4))) short  bf16x4;

#define EPSC 1e-14f

__device__ __forceinline__ short f2bf(float v) {
  __hip_bfloat16 h = __float2bfloat16(v);
  return *reinterpret_cast<short*>(&h);
}
__device__ __forceinline__ float bf2f(unsigned short u) {
  union { unsigned int i; float f; } c; c.i = ((unsigned int)u) << 16; return c.f;
}
__device__ __forceinline__ void gload16(const void* g, void* l) {
  __builtin_amdgcn_global_load_lds(
      (const __attribute__((address_space(1))) void*)g,
      (__attribute__((address_space(3))) void*)l, 16, 0, 0);
}
__device__ __forceinline__ bf16x8 cvt8(const float* p) {
  f32x4 a = *(const f32x4*)p;
  f32x4 b = *(const f32x4*)(p + 4);
  bf16x8 r;
  r[0] = f2bf(a[0]); r[1] = f2bf(a[1]); r[2] = f2bf(a[2]); r[3] = f2bf(a[3]);
  r[4] = f2bf(b[0]); r[5] = f2bf(b[1]); r[6] = f2bf(b[2]); r[7] = f2bf(b[3]);
  return r;
}

// ---------------- K0: W fp32 -> bf16 ----------------
__global__ void k0_pack(const float* __restrict__ W, short* __restrict__ Wbf) {
  int idx = blockIdx.x * 256 + threadIdx.x;
  f32x4 v = *(const f32x4*)(W + (size_t)idx * 4);
  bf16x4 pk;
  pk[0] = f2bf(v[0]); pk[1] = f2bf(v[1]); pk[2] = f2bf(v[2]); pk[3] = f2bf(v[3]);
  *(bf16x4*)(Wbf + (size_t)idx * 4) = pk;
}

// ---------------- K0b: domain uniformity check ----------------
__global__ void k0_check(const float* __restrict__ domain, float* __restrict__ flag) {
  __shared__ int s_ok[4];
  const int t = threadIdx.x;
  float v0 = domain[0];
  bool ok = true;
  for (int x = t; x < 72 * 72; x += 256) ok = ok && (domain[x] == v0);
  unsigned long long m = __ballot(ok);
  if ((t & 63) == 0) s_ok[t >> 6] = (m == ~0ull) ? 1 : 0;
  __syncthreads();
  if (t == 0) {
    flag[0] = v0;
    flag[1] = (s_ok[0] && s_ok[1] && s_ok[2] && s_ok[3]) ? 1.f : 0.f;
  }
}

// ---------------- k2a: pre-scaled weights, wave-per-row (R9-proven) ----------------
__global__ __launch_bounds__(256) void k2a_weights(
    const float* __restrict__ dist, const float* __restrict__ bear,
    const float* __restrict__ head, const float* __restrict__ seqmask,
    const float* __restrict__ domain, const float* __restrict__ uflag,
    short* __restrict__ weBuf) {
  __shared__ float sMask[256];
  const int t = threadIdx.x;
  const int b = blockIdx.x >> 3;
  const int i0 = (blockIdx.x & 7) * 32;
  if (t < 256) sMask[t] = seqmask[b * 256 + t];
  __syncthreads();

  const int w = t >> 6, l = t & 63;
  const int j0 = l * 4;
  const float dval = uflag[0];
  const bool  uni  = uflag[1] != 0.f;
  const f32x4 mj = *(const f32x4*)(sMask + j0);

  f32x4 dv[8];
  #pragma unroll
  for (int rr = 0; rr < 8; ++rr) {
    int i = i0 + w * 8 + rr;
    dv[rr] = *(const f32x4*)(dist + ((size_t)b * 256 + i) * 256 + j0);
  }

  #pragma unroll
  for (int rr = 0; rr < 8; ++rr) {
    const int i = i0 + w * 8 + rr;
    const float mI = sMask[i];
    const size_t base = ((size_t)b * 256 + i) * 256;
    float ev[4];
    float rs = 0.f;
    if (uni) {
      #pragma unroll
      for (int e = 0; e < 4; ++e) {
        float wv = fmaxf(dval - dv[rr][e], 0.f);
        bool valid = (i != j0 + e) && (mI != 0.f) && (mj[e] != 0.f);
        float ex = (wv > 0.f) ? __expf(wv) : 0.f;
        ex = valid ? ex : 0.f;
        rs += ex;
        ev[e] = valid ? (ex + EPSC) : 0.f;
      }
    } else {
      f32x4 bv = *(const f32x4*)(bear + base + j0);
      f32x4 hv = *(const f32x4*)(head + base + j0);
      #pragma unroll
      for (int e = 0; e < 4; ++e) {
        float f1 = fminf(fmaxf(floorf((hv[e] + 2.5f) * 0.2f), 0.f), 71.f);
        float f2 = fminf(fmaxf(floorf((bv[e] + 2.5f) * 0.2f), 0.f), 71.f);
        float wv = fmaxf(domain[(int)(f1 * 72.f + f2)] - dv[rr][e], 0.f);
        bool valid = (i != j0 + e) && (mI != 0.f) && (mj[e] != 0.f);
        float ex = (wv > 0.f) ? __expf(wv) : 0.f;
        ex = valid ? ex : 0.f;
        rs += ex;
        ev[e] = valid ? (ex + EPSC) : 0.f;
      }
    }
    rs += __shfl_xor(rs, 1, 64);
    rs += __shfl_xor(rs, 2, 64);
    rs += __shfl_xor(rs, 4, 64);
    rs += __shfl_xor(rs, 8, 64);
    rs += __shfl_xor(rs, 16, 64);
    rs += __shfl_xor(rs, 32, 64);
    const float scale = 1.0f / (rs + 257.0f * EPSC);
    bf16x4 pk;
    pk[0] = f2bf(ev[0] * scale); pk[1] = f2bf(ev[1] * scale);
    pk[2] = f2bf(ev[2] * scale); pk[3] = f2bf(ev[3] * scale);
    *(bf16x4*)(weBuf + base + j0) = pk;
  }
}

// ---------------- kP: P1T[b] + P2[b], B staged once per pass ----------------
// grid 256 (block = b), block 1024 = 16 waves (wr 8 x 32 rows, wc 2 x 128 d), LDS 128K.
__global__ __launch_bounds__(1024) void kP(
    const float* __restrict__ H, const short* __restrict__ Wbf,
    const float* __restrict__ bias,
    short* __restrict__ P1T, short* __restrict__ P2) {
  extern __shared__ char sm[];                 // 4 regions x [256][128B]
  const int t = threadIdx.x;
  const int b = blockIdx.x;
  const int n0 = b * 256;
  const int wid = t >> 6, l = t & 63;
  const int lr = l & 15, lg = l >> 4;
  const int wr = wid & 7, wc = wid >> 3;
  const int r3 = l >> 3, sl = l & 7;
  const int sswz = (sl ^ r3) * 8;              // source slot pre-swizzle (shorts)
  const int sw = (lr & 7) << 4;                // read-side XOR (bytes)

  const size_t h0 = ((size_t)(n0 + wr * 32 + lr)) * 256;
  const size_t h1 = h0 + 16 * 256;

  #pragma unroll
  for (int pass = 0; pass < 2; ++pass) {
    // ---- stage W-half ONCE: 4 regions x 2 sweeps of 16KB ----
    #pragma unroll
    for (int c = 0; c < 4; ++c) {
      #pragma unroll
      for (int p = 0; p < 2; ++p) {
        int dd = wid * 8 + 128 * p + r3;
        gload16(Wbf + (size_t)dd * 512 + pass * 256 + c * 64 + sswz,
                sm + c * 32768 + (wid * 8 + 128 * p) * 128);
      }
    }
    __syncthreads();                           // only barrier of the pass

    f32x4 acc[2][8] = {};
    #pragma unroll
    for (int c = 0; c < 4; ++c) {
      #pragma unroll
      for (int sub = 0; sub < 2; ++sub) {
        const int k0 = c * 64 + sub * 32 + lg * 8;
        bf16x8 av0 = cvt8(H + h0 + k0);
        bf16x8 av1 = cvt8(H + h1 + k0);
        #pragma unroll
        for (int n = 0; n < 8; ++n) {
          const int d = wc * 128 + n * 16 + lr;
          bf16x8 bb = *(const bf16x8*)(sm + c * 32768 + d * 128 + ((sub * 64 + lg * 16) ^ sw));
          acc[0][n] = __builtin_amdgcn_mfma_f32_16x16x32_bf16(av0, bb, acc[0][n], 0, 0, 0);
          acc[1][n] = __builtin_amdgcn_mfma_f32_16x16x32_bf16(av1, bb, acc[1][n], 0, 0, 0);
        }
      }
    }

    if (pass == 0) {
      // P1T[b][d][j], transposed write
      #pragma unroll
      for (int m = 0; m < 2; ++m) {
        #pragma unroll
        for (int n = 0; n < 8; ++n) {
          const int d = wc * 128 + n * 16 + lr;
          const int j = wr * 32 + m * 16 + lg * 4;
          f32x4 v = acc[m][n];
          bf16x4 pk;
          pk[0] = f2bf(v[0]); pk[1] = f2bf(v[1]); pk[2] = f2bf(v[2]); pk[3] = f2bf(v[3]);
          *(bf16x4*)(P1T + (size_t)b * 65536 + (size_t)d * 256 + j) = pk;
        }
      }
    } else {
      // P2[b][j][d] = acc + bias
      #pragma unroll
      for (int m = 0; m < 2; ++m) {
        #pragma unroll
        for (int n = 0; n < 8; ++n) {
          const int d = wc * 128 + n * 16 + lr;
          const float bs = bias[d];
          const int row = wr * 32 + m * 16 + lg * 4;
          f32x4 v = acc[m][n];
          #pragma unroll
          for (int r = 0; r < 4; ++r)
            P2[(size_t)b * 65536 + (size_t)(row + r) * 256 + d] = f2bf(v[r] + bs);
        }
      }
    }
    __syncthreads();                           // LDS reuse boundary
  }
}

// ---------------- kOut: out = weBuf @ P1T + P2, B = P1T[b] staged once ----------------
// grid 256 (block = b), block 1024, LDS 128K, 1 barrier.
__global__ __launch_bounds__(1024) void kOut(
    const short* __restrict__ weBuf, const short* __restrict__ P1T,
    const short* __restrict__ P2, float* __restrict__ out) {
  extern __shared__ char sm[];                 // 4 regions x [256][128B]
  const int t = threadIdx.x;
  const int b = blockIdx.x;
  const int wid = t >> 6, l = t & 63;
  const int lr = l & 15, lg = l >> 4;
  const int wr = wid & 7, wc = wid >> 3;
  const int r3 = l >> 3, sl = l & 7;
  const int sswz = (sl ^ r3) * 8;
  const int sw = (lr & 7) << 4;

  const short* __restrict__ P1b = P1T + (size_t)b * 65536;
  const size_t a0 = ((size_t)b * 256 + wr * 32 + lr) * 256;
  const size_t a1 = a0 + 16 * 256;

  // ---- stage P1T[b] ONCE ----
  #pragma unroll
  for (int c = 0; c < 4; ++c) {
    #pragma unroll
    for (int p = 0; p < 2; ++p) {
      int dd = wid * 8 + 128 * p + r3;
      gload16(P1b + (size_t)dd * 256 + c * 64 + sswz,
              sm + c * 32768 + (wid * 8 + 128 * p) * 128);
    }
  }
  __syncthreads();                             // the only barrier

  f32x4 acc[2][8] = {};
  #pragma unroll
  for (int c = 0; c < 4; ++c) {
    #pragma unroll
    for (int sub = 0; sub < 2; ++sub) {
      const int k0 = c * 64 + sub * 32 + lg * 8;
      bf16x8 av0 = *(const bf16x8*)(weBuf + a0 + k0);
      bf16x8 av1 = *(const bf16x8*)(weBuf + a1 + k0);
      #pragma unroll
      for (int n = 0; n < 8; ++n) {
        const int d = wc * 128 + n * 16 + lr;
        bf16x8 bb = *(const bf16x8*)(sm + c * 32768 + d * 128 + ((sub * 64 + lg * 16) ^ sw));
        acc[0][n] = __builtin_amdgcn_mfma_f32_16x16x32_bf16(av0, bb, acc[0][n], 0, 0, 0);
        acc[1][n] = __builtin_amdgcn_mfma_f32_16x16x32_bf16(av1, bb, acc[1][n], 0, 0, 0);
      }
    }
  }

  // epilogue: + P2 (bias folded), fp32 store
  #pragma unroll
  for (int m = 0; m < 2; ++m) {
    #pragma unroll
    for (int n = 0; n < 8; ++n) {
      const int d = wc * 128 + n * 16 + lr;
      const int row = wr * 32 + m * 16 + lg * 4;
      #pragma unroll
      for (int r = 0; r < 4; ++r) {
        const size_t off = ((size_t)b * 256 + row + r) * 256 + d;
        out[off] = acc[m][n][r] + bf2f((unsigned short)P2[off]);
      }
    }
  }
}

extern "C" void kernel_launch(void* const* d_in, const int* in_sizes, int n_in,
                              void* d_out, int out_size, void* d_ws, size_t ws_size,
                              hipStream_t stream) {
  const float* hidden  = (const float*)d_in[0];
  const float* dist    = (const float*)d_in[1];
  const float* bear    = (const float*)d_in[2];
  const float* head    = (const float*)d_in[3];
  const float* seqmask = (const float*)d_in[4];
  const float* domain  = (const float*)d_in[5];
  const float* W       = (const float*)d_in[6];
  const float* bias    = (const float*)d_in[7];
  float* out = (float*)d_out;

  char* ws = (char*)d_ws;
  short* Wbf   = (short*)ws;                                 // 512 KB
  float* flag  = (float*)(ws + 524288);                      // 2 floats
  short* P1T   = (short*)(ws + (1u << 20));                  // 32 MB
  short* P2    = (short*)(ws + (1u << 20) + (32u << 20));    // 32 MB
  short* weBuf = (short*)(ws + (1u << 20) + (64u << 20));    // 32 MB

  k0_pack<<<128, 256, 0, stream>>>(W, Wbf);
  k0_check<<<1, 256, 0, stream>>>(domain, flag);
  k2a_weights<<<2048, 256, 0, stream>>>(dist, bear, head, seqmask, domain, flag, weBuf);
  kP<<<256, 1024, 131072, stream>>>(hidden, Wbf, bias, P1T, P2);
  kOut<<<256, 1024, 131072, stream>>>(weBuf, P1T, P2, out);
}